// Round 6
// baseline (197.607 us; speedup 1.0000x reference)
//
#include <hip/hip_runtime.h>
#include <math.h>

// Problem constants: L=4096, B=4, D=1024, N=16
#define D_SZ 1024
#define CH 4096          // B*D channels
#define ROW 4096         // x stride between consecutive l (floats)
#define C_CHUNKS 128
#define LC 32            // L / C_CHUNKS
#define SQ_LC 5          // log2(LC)

// ---------------------------------------------------------------------------
// Param helpers: q = 1 - sigmoid(delta)*sigmoid(alpha); w = sigmoid(delta)*beta*gamma*0.25
// ---------------------------------------------------------------------------
__device__ __forceinline__ void load16(const float* __restrict__ p, int d, float v[16]) {
    const float4* p4 = (const float4*)(p + (size_t)d * 16);
#pragma unroll
    for (int r = 0; r < 4; ++r) {
        float4 t = p4[r];
        v[4*r+0] = t.x; v[4*r+1] = t.y; v[4*r+2] = t.z; v[4*r+3] = t.w;
    }
}

__device__ __forceinline__ void compute_qw(const float* __restrict__ delta,
                                           const float* __restrict__ alpha,
                                           const float* __restrict__ beta,
                                           const float* __restrict__ gamma,
                                           int d, float q[16], float w[16]) {
    float dl[16], al[16], bt[16], gm[16];
    load16(delta, d, dl); load16(alpha, d, al);
    load16(beta, d, bt);  load16(gamma, d, gm);
#pragma unroll
    for (int n = 0; n < 16; ++n) {
        float p  = 1.0f / (1.0f + __expf(-dl[n]));
        float sa = 1.0f / (1.0f + __expf(-al[n]));
        q[n] = 1.0f - p * sa;
        w[n] = p * bt[n] * gm[n] * 0.25f;   // scale = 1/sqrt(16)
    }
}

// 8-wide load group (issued as a batch; two groups kept live = 16 loads in flight)
__device__ __forceinline__ void loadg(const float* __restrict__ xp, int g, float v[8]) {
#pragma unroll
    for (int u = 0; u < 8; ++u) v[u] = xp[(size_t)(g * 8 + u) * ROW];
}

__device__ __forceinline__ void compg(float h[16], const float q[16], const float v[8]) {
#pragma unroll
    for (int u = 0; u < 8; ++u) {
        float xu = v[u];
#pragma unroll
        for (int n = 0; n < 16; ++n) h[n] = fmaf(q[n], h[n], xu);
    }
}

// ---------------------------------------------------------------------------
// Phase 1: chunk-local end state (h from 0). S[(j*CH + c)*16 + n]
// ---------------------------------------------------------------------------
__global__ __launch_bounds__(256) void k_phase1(const float* __restrict__ x,
    float* __restrict__ S,
    const float* __restrict__ delta, const float* __restrict__ alpha,
    const float* __restrict__ beta, const float* __restrict__ gamma) {
    int tid = threadIdx.x;
    int j = blockIdx.x;                  // chunk
    int c = blockIdx.y * 256 + tid;      // channel
    int d = c & (D_SZ - 1);
    float q[16], w[16];
    compute_qw(delta, alpha, beta, gamma, d, q, w);   // w dead -> DCE
    float h[16];
#pragma unroll
    for (int n = 0; n < 16; ++n) h[n] = 0.0f;
    const float* xp = x + (size_t)j * LC * ROW + c;
    float xa[8], xb[8];
    loadg(xp, 0, xa);
    loadg(xp, 1, xb); compg(h, q, xa);
    loadg(xp, 2, xa); compg(h, q, xb);
    loadg(xp, 3, xb); compg(h, q, xa);
    compg(h, q, xb);
    float4* Sp = (float4*)(S + ((size_t)j * CH + c) * 16);
#pragma unroll
    for (int r = 0; r < 4; ++r)
        Sp[r] = make_float4(h[4*r], h[4*r+1], h[4*r+2], h[4*r+3]);
}

// ---------------------------------------------------------------------------
// Phase 2: one wave per channel; lane handles chunks {2i, 2i+1}.
// Affine composition: A = q^LC, pair map h_out = A^2 h_in + (A*S_2i + S_2i+1).
// Kogge-Stone over 64 lanes, then rewrite S with per-chunk carry-IN.
// ---------------------------------------------------------------------------
__global__ __launch_bounds__(256) void k_phase2(float* __restrict__ S,
    const float* __restrict__ delta, const float* __restrict__ alpha) {
    int lane = threadIdx.x & 63;
    int wv   = threadIdx.x >> 6;            // 0..3
    int c    = blockIdx.x * 4 + wv;         // channel
    int d    = c & (D_SZ - 1);
    float dl[16], al[16];
    load16(delta, d, dl); load16(alpha, d, al);
    float A[16], pw[16];
#pragma unroll
    for (int n = 0; n < 16; ++n) {
        float p  = 1.0f / (1.0f + __expf(-dl[n]));
        float sa = 1.0f / (1.0f + __expf(-al[n]));
        float qn = 1.0f - p * sa;
#pragma unroll
        for (int t = 0; t < SQ_LC; ++t) qn *= qn;    // q^LC
        A[n]  = qn;
        pw[n] = qn * qn;                             // q^(2*LC)
    }
    float4* Spa = (float4*)(S + ((size_t)(2 * lane)     * CH + c) * 16);
    float4* Spb = (float4*)(S + ((size_t)(2 * lane + 1) * CH + c) * 16);
    float sa16[16], sb16[16];
#pragma unroll
    for (int r = 0; r < 4; ++r) {
        float4 ta = Spa[r], tb = Spb[r];
        sa16[4*r] = ta.x; sa16[4*r+1] = ta.y; sa16[4*r+2] = ta.z; sa16[4*r+3] = ta.w;
        sb16[4*r] = tb.x; sb16[4*r+1] = tb.y; sb16[4*r+2] = tb.z; sb16[4*r+3] = tb.w;
    }
    float hh[16];
#pragma unroll
    for (int n = 0; n < 16; ++n) hh[n] = fmaf(A[n], sa16[n], sb16[n]);  // pair composite
#pragma unroll
    for (int k = 1; k <= 32; k <<= 1) {
        float prev[16];
#pragma unroll
        for (int n = 0; n < 16; ++n) prev[n] = __shfl_up(hh[n], (unsigned)k, 64);
#pragma unroll
        for (int n = 0; n < 16; ++n) hh[n] = (lane >= k) ? fmaf(pw[n], prev[n], hh[n]) : hh[n];
#pragma unroll
        for (int n = 0; n < 16; ++n) pw[n] *= pw[n];
    }
    float Hb[16];                                    // state before chunk 2i
#pragma unroll
    for (int n = 0; n < 16; ++n) {
        float t = __shfl_up(hh[n], 1u, 64);
        Hb[n] = (lane == 0) ? 0.0f : t;
    }
    // carry-in(2i) = Hb; carry-in(2i+1) = A*Hb + S_2i
#pragma unroll
    for (int r = 0; r < 4; ++r) {
        Spa[r] = make_float4(Hb[4*r], Hb[4*r+1], Hb[4*r+2], Hb[4*r+3]);
        Spb[r] = make_float4(fmaf(A[4*r],   Hb[4*r],   sa16[4*r]),
                             fmaf(A[4*r+1], Hb[4*r+1], sa16[4*r+1]),
                             fmaf(A[4*r+2], Hb[4*r+2], sa16[4*r+2]),
                             fmaf(A[4*r+3], Hb[4*r+3], sa16[4*r+3]));
    }
}

// ---------------------------------------------------------------------------
// Phase 3: recurrence seeded with carry-in; out = silu(sum_n w_n h_n + x*omega)
// ---------------------------------------------------------------------------
__device__ __forceinline__ void comp_store(float h[16], const float q[16], const float w[16],
                                           float om, const float v[8],
                                           float* __restrict__ outp, int g) {
#pragma unroll
    for (int u = 0; u < 8; ++u) {
        float xu = v[u];
        float y0 = 0.0f, y1 = 0.0f, y2 = 0.0f, y3 = 0.0f;
#pragma unroll
        for (int n = 0; n < 16; n += 4) {
            h[n]   = fmaf(q[n],   h[n],   xu); y0 = fmaf(w[n],   h[n],   y0);
            h[n+1] = fmaf(q[n+1], h[n+1], xu); y1 = fmaf(w[n+1], h[n+1], y1);
            h[n+2] = fmaf(q[n+2], h[n+2], xu); y2 = fmaf(w[n+2], h[n+2], y2);
            h[n+3] = fmaf(q[n+3], h[n+3], xu); y3 = fmaf(w[n+3], h[n+3], y3);
        }
        float z = (y0 + y1) + (y2 + y3) + xu * om;
        outp[(size_t)(g * 8 + u) * ROW] = z / (1.0f + __expf(-z));   // silu
    }
}

__global__ __launch_bounds__(256) void k_phase3(const float* __restrict__ x,
    const float* __restrict__ S, float* __restrict__ out,
    const float* __restrict__ delta, const float* __restrict__ alpha,
    const float* __restrict__ beta, const float* __restrict__ gamma,
    const float* __restrict__ omega) {
    int tid = threadIdx.x;
    int j = blockIdx.x;
    int c = blockIdx.y * 256 + tid;
    int d = c & (D_SZ - 1);
    float q[16], w[16];
    compute_qw(delta, alpha, beta, gamma, d, q, w);
    float om = omega[d];
    float h[16];
    const float4* Sp = (const float4*)(S + ((size_t)j * CH + c) * 16);
#pragma unroll
    for (int r = 0; r < 4; ++r) {
        float4 t = Sp[r];
        h[4*r] = t.x; h[4*r+1] = t.y; h[4*r+2] = t.z; h[4*r+3] = t.w;
    }
    const float* xp = x + (size_t)j * LC * ROW + c;
    float* outp = out + (size_t)j * LC * ROW + c;
    float xa[8], xb[8];
    loadg(xp, 0, xa);
    loadg(xp, 1, xb); comp_store(h, q, w, om, xa, outp, 0);
    loadg(xp, 2, xa); comp_store(h, q, w, om, xb, outp, 1);
    loadg(xp, 3, xb); comp_store(h, q, w, om, xa, outp, 2);
    comp_store(h, q, w, om, xb, outp, 3);
}

// ---------------------------------------------------------------------------
extern "C" void kernel_launch(void* const* d_in, const int* in_sizes, int n_in,
                              void* d_out, int out_size, void* d_ws, size_t ws_size,
                              hipStream_t stream) {
    const float* x     = (const float*)d_in[0];
    const float* delta = (const float*)d_in[1];
    const float* alpha = (const float*)d_in[2];
    const float* beta  = (const float*)d_in[3];
    const float* gamma = (const float*)d_in[4];
    const float* omega = (const float*)d_in[5];
    float* out = (float*)d_out;
    float* S   = (float*)d_ws;   // 128*4096*16*4B = 33.5 MB (ws is ~268 MB)

    dim3 grid13(C_CHUNKS, CH / 256);   // (128,16) = 2048 blocks
    k_phase1<<<grid13, 256, 0, stream>>>(x, S, delta, alpha, beta, gamma);
    k_phase2<<<CH / 4, 256, 0, stream>>>(S, delta, alpha);
    k_phase3<<<grid13, 256, 0, stream>>>(x, S, out, delta, alpha, beta, gamma, omega);
}